// Round 13
// baseline (69.292 us; speedup 1.0000x reference)
//
#include <hip/hip_runtime.h>

typedef _Float16 f16x2 __attribute__((ext_vector_type(2)));
typedef _Float16 f16x8 __attribute__((ext_vector_type(8)));
typedef __fp16   fp16v2 __attribute__((ext_vector_type(2)));   // cvt_pkrtz return type
typedef float    f32x16 __attribute__((ext_vector_type(16)));
typedef unsigned int u32x4 __attribute__((ext_vector_type(4)));

#define TROWSTR 25   // T row stride in words (coprime 32 -> conflict-free epilogue)
#define REP 3        // DIAGNOSTIC: repeat full computation to push dispatch >40us
                     // so rocprof top-5 finally shows OUR kernel's counters.

__device__ __forceinline__ f16x2 pk2(float lo, float hi) {
    fp16v2 p = __builtin_amdgcn_cvt_pkrtz(lo, hi);
    return __builtin_bit_cast(f16x2, p);
}
__device__ __forceinline__ unsigned int pkbits(f16x2 a, f16x2 b) {
    f16x2 r = a * b;
    return __builtin_bit_cast(unsigned int, r);
}

// ---- prep: C (f32) -> flattened-K f16 B table (validated R10) ----
// wsB[s*64 + l][e] = f16(C[i][kk]), i = l&31 (0 if i>=24), kk = 16s + 8*(l>>5) + e
__global__ __launch_bounds__(256) void prep_B(const float* __restrict__ coeffs,
                                              f16x8* __restrict__ wsB)
{
    int chunk = blockIdx.x * 256 + threadIdx.x;   // 0..2303 = 36 steps * 64 lanes
    int s = chunk >> 6, l = chunk & 63;
    int i = l & 31, h = l >> 5;
    f16x8 v;
    if (i < 24) {
        const float* src = coeffs + i * 576 + 16 * s + 8 * h;
#pragma unroll
        for (int e = 0; e < 8; ++e) v[e] = (_Float16)src[e];
    } else {
#pragma unroll
        for (int e = 0; e < 8; ++e) v[e] = (_Float16)0.f;
    }
    wsB[chunk] = v;
}

// ---- main: R12 persistent-wave structure, REP=3 diagnostic, 2 acc chains ----
// Each wave: 256 points = 8 iters of one 32x32 M-tile; B (35 frags) in registers.
// Step s (1..35), elem e: kk = 16s+8h+e; j=(2s+h)/3, k=8*((2s+h)%3)+e (validated).
// acc split into even/odd-s chains to double MFMA chain ILP (latency probe).
__global__ __launch_bounds__(256, 2) void fourier_main(
    const float* __restrict__ xyz,
    const f16x8* __restrict__ wsB,
    float* __restrict__ out)
{
    __shared__ __align__(16) float Tl[4 * 32 * TROWSTR];   // 12800 B, wave-private

    const int tid  = threadIdx.x;
    const int wave = tid >> 6;
    const int lane = tid & 63;
    const int h    = lane >> 5;
    const int mr   = lane & 31;
    const bool hb  = (h != 0);

    const int pw = (blockIdx.x * 4 + wave) * 256;   // wave's 256 points

    // persistent B: 35 fragments in registers
    f16x8 bt[36];
#pragma unroll
    for (int s = 1; s < 36; ++s) bt[s] = wsB[s * 64 + lane];

    float* Tw = Tl + wave * (32 * TROWSTR);

#pragma unroll 1
    for (int rep = 0; rep < REP; ++rep) {
        float cx = xyz[3 * (pw + mr) + 0];
        float cy = xyz[3 * (pw + mr) + 1];
        float cz = xyz[3 * (pw + mr) + 2];
        // defeat cross-rep CSE (rule #17): values pass through opaque identity
        asm volatile("" : "+v"(cx), "+v"(cy), "+v"(cz));

#pragma unroll 1
        for (int it = 0; it < 8; ++it) {
            const int pp0 = pw + it * 32;

            // prefetch next iteration's point EARLY
            int pn = (it < 7) ? (pp0 + 32 + mr) : (pw + mr);
            float nx = xyz[3 * pn + 0];
            float ny = xyz[3 * pn + 1];
            float nz = xyz[3 * pn + 2];

            // trig setup (validated R10 math)
            float s1y = __builtin_amdgcn_sinf(cy);
            float c1y = __builtin_amdgcn_cosf(cy);
            float c2y = 2.f * c1y;
            float syc = hb ? s1y : 0.f;     // (prev,cur) at s=1: j = h?1:0
            float syp = hb ? 0.f : -s1y;

            float s1 = __builtin_amdgcn_sinf(cz);
            float c1 = __builtin_amdgcn_cosf(cz);
            float w8 = __builtin_amdgcn_fractf(8.f * cz);
            float s8 = __builtin_amdgcn_sinf(w8);
            float c8 = __builtin_amdgcn_cosf(w8);
            float s16 = 2.f * s8 * c8;
            float c16 = fmaf(2.f * c8, c8, -1.f);
            float c2z = 2.f * c1;

            f16x2 szR[3][4];   // rotated bank t holds k0 = 8*((t+h)%3)
#pragma unroll
            for (int t = 0; t < 3; ++t) {
                float sk, ck;
                if (t == 0) { sk = hb ? s8  : 0.f;  ck = hb ? c8  : 1.f;  }
                if (t == 1) { sk = hb ? s16 : s8;   ck = hb ? c16 : c8;   }
                if (t == 2) { sk = hb ? 0.f : s16;  ck = hb ? 1.f : c16;  }
                float v[8];
                v[0] = sk;
                v[1] = fmaf(sk, c1, ck * s1);
#pragma unroll
                for (int e = 2; e < 8; ++e) v[e] = fmaf(c2z, v[e - 1], -v[e - 2]);
#pragma unroll
                for (int q = 0; q < 4; ++q) szR[t][q] = pk2(v[2 * q], v[2 * q + 1]);
            }

            f32x16 accA = {};   // odd s
            f32x16 accB = {};   // even s (independent chain, 2x MFMA ILP)

#pragma unroll
            for (int s = 1; s < 36; ++s) {
                const int t = (2 * s) % 3;
                f16x2 hy2 = pk2(syc, syc);
                u32x4 aw;
                aw[0] = pkbits(hy2, szR[t][0]);
                aw[1] = pkbits(hy2, szR[t][1]);
                aw[2] = pkbits(hy2, szR[t][2]);
                aw[3] = pkbits(hy2, szR[t][3]);
                f16x8 a = __builtin_bit_cast(f16x8, aw);
                if (s & 1) accA = __builtin_amdgcn_mfma_f32_32x32x16_f16(a, bt[s], accA, 0, 0, 0);
                else       accB = __builtin_amdgcn_mfma_f32_32x32x16_f16(a, bt[s], accB, 0, 0, 0);
                if (s < 35) {
                    float t1 = fmaf(c2y, syc, -syp);
                    if ((s % 3) == 2) { syp = syc; syc = t1; }
                    else {
                        bool stay = ((s % 3) == 0) ? !hb : hb;
                        float np = stay ? syp : syc;
                        float nc = stay ? syc : t1;
                        syp = np; syc = nc;
                    }
                }
            }

            // scatter T (wave-private): D row=(r&3)+8*(r>>2)+4h, col=mr
            if (mr < 24) {
#pragma unroll
                for (int r = 0; r < 16; ++r) {
                    int row = (r & 3) + 8 * (r >> 2) + 4 * h;
                    Tw[row * TROWSTR + mr] = accA[r] + accB[r];
                }
            }
            asm volatile("s_waitcnt lgkmcnt(0)" ::: "memory");

            // epilogue: both halves compute row mr; lanes<32 store
            {
                float sx1 = __builtin_amdgcn_sinf(cx);
                float cx1 = __builtin_amdgcn_cosf(cx);
                const float c2x = 2.f * cx1;
                const float* Tr = Tw + mr * TROWSTR;
                float sp = 0.f, sc = sx1, res = 0.f;
#pragma unroll
                for (int i = 1; i < 24; ++i) {
                    res = fmaf(sc, Tr[i], res);
                    float nxr = fmaf(c2x, sc, -sp);
                    sp = sc; sc = nxr;
                }
                if (lane < 32) out[pp0 + mr] = res;
            }

            cx = nx; cy = ny; cz = nz;
        }
    }
}

extern "C" void kernel_launch(void* const* d_in, const int* in_sizes, int n_in,
                              void* d_out, int out_size, void* d_ws, size_t ws_size,
                              hipStream_t stream) {
    const float* xyz    = (const float*)d_in[0];
    const float* coeffs = (const float*)d_in[1];
    float* out = (float*)d_out;
    f16x8* wsB = (f16x8*)d_ws;                 // needs 36864 B

    prep_B<<<9, 256, 0, stream>>>(coeffs, wsB);

    const int n = in_sizes[0] / 3;             // 524288 = 512 blocks * 4 waves * 256
    const int grid = n / 1024;
    fourier_main<<<grid, 256, 0, stream>>>(xyz, wsB, out);
}

// Round 15
// 32.365 us; speedup vs baseline: 2.1410x; 2.1410x over previous
//
#include <hip/hip_runtime.h>

typedef _Float16 f16x2 __attribute__((ext_vector_type(2)));
typedef _Float16 f16x8 __attribute__((ext_vector_type(8)));
typedef __fp16   fp16v2 __attribute__((ext_vector_type(2)));   // cvt_pkrtz return type
typedef float    f32x16 __attribute__((ext_vector_type(16)));
typedef unsigned int u32x4 __attribute__((ext_vector_type(4)));

#define TROWSTR 25   // T row stride in words (coprime 32 -> conflict-free epilogue)

__device__ __forceinline__ f16x2 pk2(float lo, float hi) {
    fp16v2 p = __builtin_amdgcn_cvt_pkrtz(lo, hi);
    return __builtin_bit_cast(f16x2, p);
}
__device__ __forceinline__ unsigned int pkbits(f16x2 a, f16x2 b) {
    f16x2 r = a * b;
    return __builtin_bit_cast(unsigned int, r);
}

// ---- prep: C (f32) -> flattened-K f16 B table (validated R10) ----
// wsB[s*64 + l][e] = f16(C[i][kk]), i = l&31 (0 if i>=24), kk = 16s + 8*(l>>5) + e
__global__ __launch_bounds__(256) void prep_B(const float* __restrict__ coeffs,
                                              f16x8* __restrict__ wsB)
{
    int chunk = blockIdx.x * 256 + threadIdx.x;   // 0..2303 = 36 steps * 64 lanes
    int s = chunk >> 6, l = chunk & 63;
    int i = l & 31, h = l >> 5;
    f16x8 v;
    if (i < 24) {
        const float* src = coeffs + i * 576 + 16 * s + 8 * h;
#pragma unroll
        for (int e = 0; e < 8; ++e) v[e] = (_Float16)src[e];
    } else {
#pragma unroll
        for (int e = 0; e < 8; ++e) v[e] = (_Float16)0.f;
    }
    wsB[chunk] = v;
}

// ---- main: 4 waves/SIMD one-round. Each wave: 128 points = 4 iters of one
// 32x32 M-tile. Flattened K (validated R10): step s (1..35), elem e:
// kk = 16s+8h+e; j=(2s+h)/3, k=8*((2s+h)%3)+e.
// T layout: T[point][i] (point=row stride TROWSTR, i=col). Epilogue h-split:
// h=0 sums i=0..11, h=1 sums i=12..23 (both for point mr), combine shfl_xor.
// Native v_sin/v_cos take REVOLUTIONS: sin(2pi*x) = __builtin_amdgcn_sinf(x).
__global__ __launch_bounds__(256, 2) void fourier_main(
    const float* __restrict__ xyz,
    const f16x8* __restrict__ wsB,
    float* __restrict__ out)
{
    __shared__ __align__(16) float Tl[4 * 32 * TROWSTR];   // 12800 B, wave-private

    const int tid  = threadIdx.x;
    const int wave = tid >> 6;
    const int lane = tid & 63;
    const int h    = lane >> 5;
    const int mr   = lane & 31;
    const bool hb  = (h != 0);

    const int pw = (blockIdx.x * 4 + wave) * 128;   // wave's 128 points

    // B fragments: compiler sinks these to per-use L2 loads (R13: VGPR=104);
    // that allocation supports 4 waves/SIMD, which this grid provides.
    f16x8 bt[36];
#pragma unroll
    for (int s = 1; s < 36; ++s) bt[s] = wsB[s * 64 + lane];

    float cx = xyz[3 * (pw + mr) + 0];
    float cy = xyz[3 * (pw + mr) + 1];
    float cz = xyz[3 * (pw + mr) + 2];

    float* Tw = Tl + wave * (32 * TROWSTR);

#pragma unroll 1
    for (int it = 0; it < 4; ++it) {
        const int pp0 = pw + it * 32;

        // prefetch next iteration's point EARLY (hides HBM under trig+MFMA)
        int pn = (it < 3) ? (pp0 + 32 + mr) : (pw + mr);
        float nx = xyz[3 * pn + 0];
        float ny = xyz[3 * pn + 1];
        float nz = xyz[3 * pn + 2];

        // ---- trig setup (R10 math) ----
        float s1y = __builtin_amdgcn_sinf(cy);
        float c1y = __builtin_amdgcn_cosf(cy);
        float c2y = 2.f * c1y;
        float syc = hb ? s1y : 0.f;     // (prev,cur) at s=1: j = h?1:0
        float syp = hb ? 0.f : -s1y;

        float s1 = __builtin_amdgcn_sinf(cz);
        float c1 = __builtin_amdgcn_cosf(cz);
        float w8 = __builtin_amdgcn_fractf(8.f * cz);
        float s8 = __builtin_amdgcn_sinf(w8);
        float c8 = __builtin_amdgcn_cosf(w8);
        float s16 = 2.f * s8 * c8;
        float c16 = fmaf(2.f * c8, c8, -1.f);
        float c2z = 2.f * c1;

        f16x2 szR[3][4];   // rotated bank t holds k0 = 8*((t+h)%3)
#pragma unroll
        for (int t = 0; t < 3; ++t) {
            float sk, ck;
            if (t == 0) { sk = hb ? s8  : 0.f;  ck = hb ? c8  : 1.f;  }
            if (t == 1) { sk = hb ? s16 : s8;   ck = hb ? c16 : c8;   }
            if (t == 2) { sk = hb ? 0.f : s16;  ck = hb ? 1.f : c16;  }
            float v[8];
            v[0] = sk;
            v[1] = fmaf(sk, c1, ck * s1);
#pragma unroll
            for (int e = 2; e < 8; ++e) v[e] = fmaf(c2z, v[e - 1], -v[e - 2]);
#pragma unroll
            for (int q = 0; q < 4; ++q) szR[t][q] = pk2(v[2 * q], v[2 * q + 1]);
        }

        f32x16 acc = {};

        // ---- main loop: A-build + MFMA ----
#pragma unroll
        for (int s = 1; s < 36; ++s) {
            const int t = (2 * s) % 3;
            f16x2 hy2 = pk2(syc, syc);
            u32x4 aw;
            aw[0] = pkbits(hy2, szR[t][0]);
            aw[1] = pkbits(hy2, szR[t][1]);
            aw[2] = pkbits(hy2, szR[t][2]);
            aw[3] = pkbits(hy2, szR[t][3]);
            f16x8 a = __builtin_bit_cast(f16x8, aw);
            acc = __builtin_amdgcn_mfma_f32_32x32x16_f16(a, bt[s], acc, 0, 0, 0);
            if (s < 35) {
                float t1 = fmaf(c2y, syc, -syp);
                if ((s % 3) == 2) { syp = syc; syc = t1; }
                else {
                    bool stay = ((s % 3) == 0) ? !hb : hb;
                    float np = stay ? syp : syc;
                    float nc = stay ? syc : t1;
                    syp = np; syc = nc;
                }
            }
        }

        // ---- scatter T[point][i]: point=D row=(r&3)+8*(r>>2)+4h, i=D col=mr ----
        if (mr < 24) {
#pragma unroll
            for (int r = 0; r < 16; ++r) {
                int row = (r & 3) + 8 * (r >> 2) + 4 * h;
                Tw[row * TROWSTR + mr] = acc[r];
            }
        }
        asm volatile("s_waitcnt lgkmcnt(0)" ::: "memory");   // wave-local drain

        // ---- epilogue, h-split over i for point mr: h half sums i=12h..12h+11 ----
        {
            float sx1 = __builtin_amdgcn_sinf(cx);
            float cx1 = __builtin_amdgcn_cosf(cx);
            const float c2x = 2.f * cx1;
            // seeds for h=1 half: s11, s12 via double/compound angle
            float w6  = __builtin_amdgcn_fractf(6.f * cx);
            float s6  = __builtin_amdgcn_sinf(w6);
            float c6  = __builtin_amdgcn_cosf(w6);
            float s12 = 2.f * s6 * c6;
            float c12 = fmaf(2.f * c6, c6, -1.f);
            float s11 = s12 * cx1 - c12 * sx1;
            // h=0 entering i=0: (sp,sc) = (sin(-x), sin(0)) = (-sx1, 0)
            float sp = hb ? s11 : -sx1;
            float sc = hb ? s12 : 0.f;
            // T[point=mr][i=12h+w]  (row mr, column step 1 — FIXED vs R14)
            const float* Tr = Tw + mr * TROWSTR + 12 * h;
            float res = 0.f;
#pragma unroll
            for (int w = 0; w < 12; ++w) {
                res = fmaf(sc, Tr[w], res);
                float nxr = fmaf(c2x, sc, -sp);
                sp = sc; sc = nxr;
            }
            res += __shfl_xor(res, 32);
            if (lane < 32) out[pp0 + mr] = res;
        }

        cx = nx; cy = ny; cz = nz;
    }
}

extern "C" void kernel_launch(void* const* d_in, const int* in_sizes, int n_in,
                              void* d_out, int out_size, void* d_ws, size_t ws_size,
                              hipStream_t stream) {
    const float* xyz    = (const float*)d_in[0];
    const float* coeffs = (const float*)d_in[1];
    float* out = (float*)d_out;
    f16x8* wsB = (f16x8*)d_ws;                 // needs 36864 B

    prep_B<<<9, 256, 0, stream>>>(coeffs, wsB);

    const int n = in_sizes[0] / 3;             // 524288 = 1024 blocks * 4 waves * 128
    const int grid = n / 512;
    fourier_main<<<grid, 256, 0, stream>>>(xyz, wsB, out);
}

// Round 16
// 31.695 us; speedup vs baseline: 2.1863x; 1.0212x over previous
//
#include <hip/hip_runtime.h>

typedef _Float16 f16x2 __attribute__((ext_vector_type(2)));
typedef _Float16 f16x8 __attribute__((ext_vector_type(8)));
typedef __fp16   fp16v2 __attribute__((ext_vector_type(2)));   // cvt_pkrtz return type
typedef float    f32x16 __attribute__((ext_vector_type(16)));
typedef unsigned int u32x4 __attribute__((ext_vector_type(4)));

#define TROWSTR 25   // T row stride in words (coprime 32 -> conflict-free epilogue)

__device__ __forceinline__ f16x2 pk2(float lo, float hi) {
    fp16v2 p = __builtin_amdgcn_cvt_pkrtz(lo, hi);
    return __builtin_bit_cast(f16x2, p);
}
__device__ __forceinline__ unsigned int pkbits(f16x2 a, f16x2 b) {
    f16x2 r = a * b;
    return __builtin_bit_cast(unsigned int, r);
}

// ---- prep: C (f32) -> flattened-K f16 B table (validated R10) ----
// wsB[s*64 + l][e] = f16(C[i][kk]), i = l&31 (0 if i>=24), kk = 16s + 8*(l>>5) + e
__global__ __launch_bounds__(256) void prep_B(const float* __restrict__ coeffs,
                                              f16x8* __restrict__ wsB)
{
    int chunk = blockIdx.x * 256 + threadIdx.x;   // 0..2303 = 36 steps * 64 lanes
    int s = chunk >> 6, l = chunk & 63;
    int i = l & 31, h = l >> 5;
    f16x8 v;
    if (i < 24) {
        const float* src = coeffs + i * 576 + 16 * s + 8 * h;
#pragma unroll
        for (int e = 0; e < 8; ++e) v[e] = (_Float16)src[e];
    } else {
#pragma unroll
        for (int e = 0; e < 8; ++e) v[e] = (_Float16)0.f;
    }
    wsB[chunk] = v;
}

// ---- main: REGISTER-PINNED persistent B (the R13 diagnosis fix).
// 2048 waves (2/SIMD), each: 256 points = 8 iters of one 32x32 M-tile.
// B: 35 frags = 140 VGPR, loaded once, pinned via opaque asm (compiler cannot
// re-materialize -> no per-iter L2 re-stream, which R13 showed was the binder).
// Flattened K (validated R10): step s (1..35), elem e: kk=16s+8h+e;
// j=(2s+h)/3 (per-half compile-time), k=8*((2s+h)%3)+e.
// sy via per-iter table (22 fma), per-step select is compile-time indexed.
// Native v_sin/v_cos take REVOLUTIONS: sin(2pi*x) = __builtin_amdgcn_sinf(x).
__global__ __launch_bounds__(256, 2) void fourier_main(
    const float* __restrict__ xyz,
    const f16x8* __restrict__ wsB,
    float* __restrict__ out)
{
    __shared__ __align__(16) float Tl[4 * 32 * TROWSTR];   // 12800 B, wave-private

    const int tid  = threadIdx.x;
    const int wave = tid >> 6;
    const int lane = tid & 63;
    const int h    = lane >> 5;
    const int mr   = lane & 31;
    const bool hb  = (h != 0);

    const int pw = (blockIdx.x * 4 + wave) * 256;   // wave's 256 points

    // ---- persistent B: load once, PIN in registers (opaque identity) ----
    u32x4 btw[36];
#pragma unroll
    for (int s = 1; s < 36; ++s) btw[s] = ((const u32x4*)wsB)[s * 64 + lane];
#pragma unroll
    for (int s = 1; s < 36; ++s) asm volatile("" : "+v"(btw[s]));

    float cx = xyz[3 * (pw + mr) + 0];
    float cy = xyz[3 * (pw + mr) + 1];
    float cz = xyz[3 * (pw + mr) + 2];

    float* Tw = Tl + wave * (32 * TROWSTR);

#pragma unroll 1
    for (int it = 0; it < 8; ++it) {
        const int pp0 = pw + it * 32;

        // prefetch next iteration's point EARLY (hides HBM under trig+MFMA)
        int pn = (it < 7) ? (pp0 + 32 + mr) : (pw + mr);
        float nx = xyz[3 * pn + 0];
        float ny = xyz[3 * pn + 1];
        float nz = xyz[3 * pn + 2];

        // ---- trig setup ----
        float s1y = __builtin_amdgcn_sinf(cy);
        float c1y = __builtin_amdgcn_cosf(cy);
        float c2y = 2.f * c1y;
        // full sy table, statically indexed only (22 fma, no cndmask)
        float syv[24];
        syv[0] = 0.f; syv[1] = s1y;
#pragma unroll
        for (int j = 2; j < 24; ++j) syv[j] = fmaf(c2y, syv[j - 1], -syv[j - 2]);

        float s1 = __builtin_amdgcn_sinf(cz);
        float c1 = __builtin_amdgcn_cosf(cz);
        float w8 = __builtin_amdgcn_fractf(8.f * cz);
        float s8 = __builtin_amdgcn_sinf(w8);
        float c8 = __builtin_amdgcn_cosf(w8);
        float s16 = 2.f * s8 * c8;
        float c16 = fmaf(2.f * c8, c8, -1.f);
        float c2z = 2.f * c1;

        f16x2 szR[3][4];   // rotated bank t holds k0 = 8*((t+h)%3)  (validated)
#pragma unroll
        for (int t = 0; t < 3; ++t) {
            float sk, ck;
            if (t == 0) { sk = hb ? s8  : 0.f;  ck = hb ? c8  : 1.f;  }
            if (t == 1) { sk = hb ? s16 : s8;   ck = hb ? c16 : c8;   }
            if (t == 2) { sk = hb ? 0.f : s16;  ck = hb ? 1.f : c16;  }
            float v[8];
            v[0] = sk;
            v[1] = fmaf(sk, c1, ck * s1);
#pragma unroll
            for (int e = 2; e < 8; ++e) v[e] = fmaf(c2z, v[e - 1], -v[e - 2]);
#pragma unroll
            for (int q = 0; q < 4; ++q) szR[t][q] = pk2(v[2 * q], v[2 * q + 1]);
        }

        f32x16 acc = {};

        // ---- main loop: pure register VALU + MFMA (B pinned, no loads) ----
#pragma unroll
        for (int s = 1; s < 36; ++s) {
            const int t  = (2 * s) % 3;
            const int j0 = (2 * s) / 3;        // h=0 j   (compile-time)
            const int j1 = (2 * s + 1) / 3;    // h=1 j   (compile-time)
            float hy = (j0 == j1) ? syv[j0] : (hb ? syv[j1] : syv[j0]);
            f16x2 hy2 = pk2(hy, hy);
            u32x4 aw;
            aw[0] = pkbits(hy2, szR[t][0]);
            aw[1] = pkbits(hy2, szR[t][1]);
            aw[2] = pkbits(hy2, szR[t][2]);
            aw[3] = pkbits(hy2, szR[t][3]);
            f16x8 a = __builtin_bit_cast(f16x8, aw);
            f16x8 b = __builtin_bit_cast(f16x8, btw[s]);
            acc = __builtin_amdgcn_mfma_f32_32x32x16_f16(a, b, acc, 0, 0, 0);
        }

        // ---- scatter T[point][i]: point=D row=(r&3)+8*(r>>2)+4h, i=D col=mr ----
        if (mr < 24) {
#pragma unroll
            for (int r = 0; r < 16; ++r) {
                int row = (r & 3) + 8 * (r >> 2) + 4 * h;
                Tw[row * TROWSTR + mr] = acc[r];
            }
        }
        asm volatile("s_waitcnt lgkmcnt(0)" ::: "memory");   // wave-local drain

        // ---- epilogue, h-split over i: h half sums i=12h..12h+11 (validated R15) ----
        {
            float sx1 = __builtin_amdgcn_sinf(cx);
            float cx1 = __builtin_amdgcn_cosf(cx);
            const float c2x = 2.f * cx1;
            float w6  = __builtin_amdgcn_fractf(6.f * cx);
            float s6  = __builtin_amdgcn_sinf(w6);
            float c6  = __builtin_amdgcn_cosf(w6);
            float s12 = 2.f * s6 * c6;
            float c12 = fmaf(2.f * c6, c6, -1.f);
            float s11 = s12 * cx1 - c12 * sx1;
            float sp = hb ? s11 : -sx1;
            float sc = hb ? s12 : 0.f;
            const float* Tr = Tw + mr * TROWSTR + 12 * h;
            float res = 0.f;
#pragma unroll
            for (int w = 0; w < 12; ++w) {
                res = fmaf(sc, Tr[w], res);
                float nxr = fmaf(c2x, sc, -sp);
                sp = sc; sc = nxr;
            }
            res += __shfl_xor(res, 32);
            if (lane < 32) out[pp0 + mr] = res;
        }

        cx = nx; cy = ny; cz = nz;
    }
}

extern "C" void kernel_launch(void* const* d_in, const int* in_sizes, int n_in,
                              void* d_out, int out_size, void* d_ws, size_t ws_size,
                              hipStream_t stream) {
    const float* xyz    = (const float*)d_in[0];
    const float* coeffs = (const float*)d_in[1];
    float* out = (float*)d_out;
    f16x8* wsB = (f16x8*)d_ws;                 // needs 36864 B

    prep_B<<<9, 256, 0, stream>>>(coeffs, wsB);

    const int n = in_sizes[0] / 3;             // 524288 = 512 blocks * 4 waves * 256
    const int grid = n / 1024;
    fourier_main<<<grid, 256, 0, stream>>>(xyz, wsB, out);
}